// Round 10
// baseline (362.692 us; speedup 1.0000x reference)
//
#include <hip/hip_runtime.h>

// ---- problem constants ----
#define B_   2
#define L_   4096
#define DM   768
#define DI   1536     // D_INNER
#define DS   64       // D_STATE
#define H_   24       // NHEADS
#define P_   64       // HEADDIM
#define CD   1664     // CONV_DIM
#define NPJ  3224     // D_IN_PROJ
#define N1   3200     // GEMM1 cols (z | xBC merged); dt cols exact in k_dt2
#define Q_   64       // chunk length
#define NC   64       // chunks per batch
#define SP   76       // LDS row stride (floats) for k_inter tiles
#define HS   72       // fp16 LDS row stride (halves): <=2-way conflicts
#define WDS  772      // k_dt2 LDS W stride
#define CROWS 16      // conv rows per thread

typedef short          bf16x8 __attribute__((ext_vector_type(8)));
typedef _Float16       f16x8  __attribute__((ext_vector_type(8)));
typedef unsigned short us8    __attribute__((ext_vector_type(8)));
typedef float          f32x4  __attribute__((ext_vector_type(4)));

__device__ __forceinline__ unsigned short f2bf(float f) {
  unsigned u = __float_as_uint(f);
  u += 0x7fffu + ((u >> 16) & 1u);   // RNE
  return (unsigned short)(u >> 16);
}
__device__ __forceinline__ float bf2f(unsigned short u) {
  return __uint_as_float(((unsigned)u) << 16);
}
__device__ __forceinline__ float siluf(float x) { return x / (1.f + expf(-x)); }
__device__ __forceinline__ float softplusf(float x) { return (x > 20.f) ? x : log1pf(expf(x)); }

__device__ __forceinline__ void gload16(const unsigned short* g, unsigned short* l) {
  __builtin_amdgcn_global_load_lds(
      (const __attribute__((address_space(1))) void*)g,
      (__attribute__((address_space(3))) void*)l, 16, 0, 0);
}

// ---------------- transpose + cast (R x C fp32) -> (C x R bf16) ----------------
__global__ __launch_bounds__(256)
void k_transpose_cast(const float* __restrict__ src, unsigned short* __restrict__ dst,
                      int R, int C)
{
  __shared__ float tile[32][33];
  const int tx = threadIdx.x & 31, ty = threadIdx.x >> 5;
  const int r0 = blockIdx.x * 32, c0 = blockIdx.y * 32;
#pragma unroll
  for (int r = 0; r < 4; ++r) {
    int rr = r0 + ty + r * 8, cc = c0 + tx;
    if (rr < R && cc < C) tile[ty + r * 8][tx] = src[(size_t)rr * C + cc];
  }
  __syncthreads();
#pragma unroll
  for (int r = 0; r < 4; ++r) {
    int orow = c0 + ty + r * 8, ocol = r0 + tx;
    if (orow < C && ocol < R) dst[(size_t)orow * R + ocol] = f2bf(tile[tx][ty + r * 8]);
  }
}

// ---------------- gather dt columns of W_in -> contiguous fp32 WdtT[24][768] ----------------
__global__ void k_wdtT(const float* __restrict__ W_in, float* __restrict__ WdtT)
{
  const int idx = blockIdx.x * 256 + threadIdx.x;
  if (idx >= H_ * DM) return;
  const int k = idx / H_, h = idx % H_;
  WdtT[(size_t)h * DM + k] = W_in[(size_t)k * NPJ + N1 + h];
}

// ---------------- bf16 MFMA GEMM, templated BK, XOR-swizzled LDS ----------------
// C(MxN) = A(MxK) @ Bt(NxK)^T, single output.
template<int BM, int BN, int WM, int WN, int BK, bool OUT_BF16>
__global__ __launch_bounds__(256)
void k_gemm_t(const unsigned short* __restrict__ A, const unsigned short* __restrict__ Bt,
              void* __restrict__ Cv, int ldc, int K)
{
  constexpr int MI = WM / 16, NI = WN / 16, KS = BK / 32;
  constexpr int WAVES_N = BN / WN;
  constexpr int RPC = (BK == 64) ? 8 : 4;     // rows per wave-call
  constexpr int CPC = 64 / RPC;               // 16B chunks per row half
  constexpr int RA = BM / (4 * RPC), RB = BN / (4 * RPC);
  const int m0 = blockIdx.x * BM, n0 = blockIdx.y * BN;
  __shared__ unsigned short As[BM][BK];
  __shared__ unsigned short Bs[BN][BK];
  const int tid  = threadIdx.x;
  const int wave = tid >> 6, lane = tid & 63;
  const int quad = lane >> 4, r16 = lane & 15;
  const int wm = (wave / WAVES_N) * WM, wn = (wave % WAVES_N) * WN;

  const int lrr = lane / CPC;                 // row within wave-call
  const int lcc = lane % CPC;                 // 16B chunk within row

  f32x4 acc[MI][NI];
#pragma unroll
  for (int mi = 0; mi < MI; ++mi)
#pragma unroll
    for (int ni = 0; ni < NI; ++ni) acc[mi][ni] = (f32x4){0.f, 0.f, 0.f, 0.f};

  for (int k0 = 0; k0 < K; k0 += BK) {
#pragma unroll
    for (int r = 0; r < RA; ++r) {
      const int row = r * 4 * RPC + wave * RPC + lrr;
      const int csw = ((lcc ^ (row & 7)) * 8);
      gload16(A + (size_t)(m0 + row) * K + k0 + csw,
              &As[r * 4 * RPC + wave * RPC][0] + (size_t)lane * 8);
    }
#pragma unroll
    for (int r = 0; r < RB; ++r) {
      const int row = r * 4 * RPC + wave * RPC + lrr;
      const int csw = ((lcc ^ (row & 7)) * 8);
      gload16(Bt + (size_t)(n0 + row) * K + k0 + csw,
              &Bs[r * 4 * RPC + wave * RPC][0] + (size_t)lane * 8);
    }
    __syncthreads();
#pragma unroll
    for (int ks = 0; ks < KS; ++ks) {
      bf16x8 af[MI], bfr[NI];
#pragma unroll
      for (int mi = 0; mi < MI; ++mi)
        af[mi] = *(const bf16x8*)&As[wm + mi * 16 + r16][((quad + ks * 4) ^ (r16 & 7)) * 8];
#pragma unroll
      for (int ni = 0; ni < NI; ++ni)
        bfr[ni] = *(const bf16x8*)&Bs[wn + ni * 16 + r16][((quad + ks * 4) ^ (r16 & 7)) * 8];
#pragma unroll
      for (int mi = 0; mi < MI; ++mi)
#pragma unroll
        for (int ni = 0; ni < NI; ++ni)
          acc[mi][ni] = __builtin_amdgcn_mfma_f32_16x16x32_bf16(
              af[mi], bfr[ni], acc[mi][ni], 0, 0, 0);
    }
    __syncthreads();
  }
#pragma unroll
  for (int mi = 0; mi < MI; ++mi)
#pragma unroll
    for (int ni = 0; ni < NI; ++ni) {
      const int col = n0 + wn + ni * 16 + r16;
#pragma unroll
      for (int r = 0; r < 4; ++r) {
        const int row = m0 + wm + mi * 16 + quad * 4 + r;
        if (OUT_BF16) ((unsigned short*)Cv)[(size_t)row * ldc + col] = f2bf(acc[mi][ni][r]);
        else          ((float*)Cv)[(size_t)row * ldc + col] = acc[mi][ni][r];
      }
    }
}

// ---------------- depthwise conv(4) + silu: sliding window over zx's xBC cols ----------------
__global__ __launch_bounds__(256)
void k_conv2(const unsigned short* __restrict__ zx, const float* __restrict__ cw,
             const float* __restrict__ cb, _Float16* __restrict__ xs,
             _Float16* __restrict__ Bm, _Float16* __restrict__ Cm)
{
  const int ch = blockIdx.x * 256 + threadIdx.x;
  if (ch >= CD) return;
  const unsigned short* xbc = zx + DI;        // col offset; row stride N1
  const int r0 = blockIdx.y * CROWS;
  const float w0 = cw[ch * 4], w1 = cw[ch * 4 + 1], w2 = cw[ch * 4 + 2], w3 = cw[ch * 4 + 3];
  const float bias = cb[ch];
  float a, b, c;
  if ((r0 & (L_ - 1)) == 0) {                 // batch start: zero history
    a = 0.f; b = 0.f; c = 0.f;
  } else {
    a = bf2f(xbc[(size_t)(r0 - 3) * N1 + ch]);
    b = bf2f(xbc[(size_t)(r0 - 2) * N1 + ch]);
    c = bf2f(xbc[(size_t)(r0 - 1) * N1 + ch]);
  }
#pragma unroll
  for (int i = 0; i < CROWS; ++i) {
    const int lr = r0 + i;
    float d = bf2f(xbc[(size_t)lr * N1 + ch]);
    float v = siluf(bias + a * w0 + b * w1 + c * w2 + d * w3);
    a = b; b = c; c = d;
    if (ch < DI)           xs[(size_t)lr * DI + ch] = (_Float16)v;
    else if (ch < DI + DS) Bm[(size_t)lr * DS + (ch - DI)] = (_Float16)v;
    else                   Cm[(size_t)lr * DS + (ch - DI - DS)] = (_Float16)v;
  }
}

// ---------------- exact fp32 dt via LDS-staged WdtT + fused x->bf16 cast ----------------
__global__ __launch_bounds__(192)
void k_dt2(const float* __restrict__ x, const float* __restrict__ WdtT,
           const float* __restrict__ dt_bias, float* __restrict__ dtv,
           unsigned short* __restrict__ xb)
{
  __shared__ float sW[H_][WDS];
  for (int i = threadIdx.x; i < H_ * DM; i += 192)
    sW[i / DM][i % DM] = WdtT[i];
  const int h = threadIdx.x % H_, rloc = threadIdx.x / H_;
  const int lrow = blockIdx.x * 8 + rloc;
  const float* xr = x + (size_t)lrow * DM;
  __syncthreads();
  float acc = 0.f;
#pragma unroll 8
  for (int k = 0; k < DM; k += 4) {
    f32x4 xv = *(const f32x4*)(xr + k);
    f32x4 wv = *(const f32x4*)&sW[h][k];
    acc += xv[0] * wv[0] + xv[1] * wv[1] + xv[2] * wv[2] + xv[3] * wv[3];
  }
  dtv[(size_t)lrow * H_ + h] = softplusf(acc + dt_bias[h]);
  const float* xi = xr + h * 32;
  unsigned short* xo = xb + (size_t)lrow * DM + h * 32;
#pragma unroll
  for (int j = 0; j < 32; j += 8) {
    f32x4 a = *(const f32x4*)(xi + j);
    f32x4 b = *(const f32x4*)(xi + j + 4);
    us8 o;
#pragma unroll
    for (int e = 0; e < 4; ++e) { o[e] = f2bf(a[e]); o[e + 4] = f2bf(b[e]); }
    *(us8*)(xo + j) = o;
  }
}

// ---------------- intra-chunk via fp16 MFMA; local cumsum; ytot/Sbuf fp16 ----------------
__global__ __launch_bounds__(256)
void k_intra(const _Float16* __restrict__ xs, const _Float16* __restrict__ Bm,
             const _Float16* __restrict__ Cm, const float* __restrict__ dtv,
             const float* __restrict__ A_log, _Float16* __restrict__ ytot,
             _Float16* __restrict__ Sbuf, float* __restrict__ decb)
{
  const int c = blockIdx.x, h = blockIdx.y, bz = blockIdx.z;
  const int gidx = (bz * H_ + h) * NC + c;
  __shared__ _Float16 sCW[Q_][HS];   // C, then W
  __shared__ _Float16 sB [Q_][HS];
  __shared__ _Float16 sBT[Q_][HS];   // (coef_j * B[j][n]) transposed -> [n][j]
  __shared__ _Float16 sXT[Q_][HS];   // X transposed -> [p][j]
  __shared__ float scum[Q_], sdt[Q_];
  const int tid = threadIdx.x;
  const int rowbase = bz * L_ + c * Q_;

  {
    const int j = tid >> 2, s16 = (tid & 3) * 16;
    if (tid < Q_) {
      float ld = dtv[(size_t)(rowbase + tid) * H_ + h];
      sdt[tid] = ld;
      const float A = -expf(A_log[h]);
      float v = ld * A;
#pragma unroll
      for (int off = 1; off < 64; off <<= 1) {
        float n = __shfl_up(v, off, 64);
        if (tid >= off) v += n;
      }
      scum[tid] = v;
      if (tid == Q_ - 1) decb[gidx] = expf(v);
    }
    const _Float16* xsrc = xs + (size_t)(rowbase + j) * DI + h * P_ + s16;
    f16x8 xv0 = *(const f16x8*)xsrc;
    f16x8 xv1 = *(const f16x8*)(xsrc + 8);
    const _Float16* bsrc = Bm + (size_t)(rowbase + j) * DS + s16;
    const _Float16* csrc = Cm + (size_t)(rowbase + j) * DS + s16;
    f16x8 bv0 = *(const f16x8*)bsrc;
    f16x8 bv1 = *(const f16x8*)(bsrc + 8);
    f16x8 cv0 = *(const f16x8*)csrc;
    f16x8 cv1 = *(const f16x8*)(csrc + 8);
    __syncthreads();                  // scum/sdt visible
    const float coef = expf(scum[Q_ - 1] - scum[j]) * sdt[j];
#pragma unroll
    for (int o = 0; o < 16; ++o) {
      _Float16 bh = (o < 8) ? bv0[o] : bv1[o - 8];
      sBT[s16 + o][j] = (_Float16)((float)bh * coef);
      sXT[s16 + o][j] = (o < 8) ? xv0[o] : xv1[o - 8];
    }
    *(f16x8*)&sCW[j][s16]     = cv0;
    *(f16x8*)&sCW[j][s16 + 8] = cv1;
    *(f16x8*)&sB [j][s16]     = bv0;
    *(f16x8*)&sB [j][s16 + 8] = bv1;
  }
  __syncthreads();

  const int wave = tid >> 6, lane = tid & 63;
  const int quad = lane >> 4, r16 = lane & 15;
  const int i0 = wave * 16;
  const int irow = i0 + quad * 4;

  f32x4 g[4];
#pragma unroll
  for (int q = 0; q < 4; ++q) g[q] = (f32x4){0.f, 0.f, 0.f, 0.f};
#pragma unroll
  for (int ni = 0; ni < 4; ++ni) {
    if (ni <= wave) {
#pragma unroll
      for (int ks = 0; ks < 2; ++ks)
        g[ni] = __builtin_amdgcn_mfma_f32_16x16x32_f16(
            *(const f16x8*)&sCW[i0 + r16][ks * 32 + quad * 8],
            *(const f16x8*)&sB [ni * 16 + r16][ks * 32 + quad * 8], g[ni], 0, 0, 0);
    }
  }
  float wv[4][4];
#pragma unroll
  for (int ni = 0; ni < 4; ++ni)
#pragma unroll
    for (int r = 0; r < 4; ++r) {
      int i = irow + r, jcol = ni * 16 + r16;
      float v = 0.f;
      if (ni <= wave && jcol <= i)
        v = g[ni][r] * expf(scum[i] - scum[jcol]) * sdt[jcol];
      wv[ni][r] = v;
    }
  __syncthreads();
#pragma unroll
  for (int ni = 0; ni < 4; ++ni)
#pragma unroll
    for (int r = 0; r < 4; ++r)
      sCW[irow + r][ni * 16 + r16] = (_Float16)wv[ni][r];
  __syncthreads();

  f32x4 y[4];
#pragma unroll
  for (int q = 0; q < 4; ++q) y[q] = (f32x4){0.f, 0.f, 0.f, 0.f};
#pragma unroll
  for (int ni = 0; ni < 4; ++ni)
#pragma unroll
    for (int ks = 0; ks < 2; ++ks) {
      if (ks == 0 || wave >= 2)
        y[ni] = __builtin_amdgcn_mfma_f32_16x16x32_f16(
            *(const f16x8*)&sCW[i0 + r16][ks * 32 + quad * 8],
            *(const f16x8*)&sXT[ni * 16 + r16][ks * 32 + quad * 8], y[ni], 0, 0, 0);
    }
#pragma unroll
  for (int ni = 0; ni < 4; ++ni)
#pragma unroll
    for (int r = 0; r < 4; ++r)
      ytot[(size_t)(rowbase + irow + r) * DI + h * P_ + ni * 16 + r16] = (_Float16)y[ni][r];

  f32x4 t4[4];
#pragma unroll
  for (int q = 0; q < 4; ++q) t4[q] = (f32x4){0.f, 0.f, 0.f, 0.f};
#pragma unroll
  for (int ni = 0; ni < 4; ++ni)
#pragma unroll
    for (int ks = 0; ks < 2; ++ks)
      t4[ni] = __builtin_amdgcn_mfma_f32_16x16x32_f16(
          *(const f16x8*)&sBT[i0 + r16][ks * 32 + quad * 8],
          *(const f16x8*)&sXT[ni * 16 + r16][ks * 32 + quad * 8], t4[ni], 0, 0, 0);
  _Float16* sp = Sbuf + (size_t)gidx * (DS * P_);
#pragma unroll
  for (int ni = 0; ni < 4; ++ni)
#pragma unroll
    for (int r = 0; r < 4; ++r)
      sp[(irow + r) * P_ + ni * 16 + r16] = (_Float16)t4[ni][r];
}

// ---------------- sequential inter-chunk recurrence (in-place, fp16 storage) ----------------
__global__ void k_chunkscan(_Float16* __restrict__ Sbuf, const float* __restrict__ decb)
{
  const int seg = blockIdx.x, h = blockIdx.y, bz = blockIdx.z;
  const int bh = bz * H_ + h;
  __shared__ float dec[NC];
  const int tid = threadIdx.x;
  if (tid < NC) dec[tid] = decb[bh * NC + tid];
  __syncthreads();
  const size_t off = (size_t)seg * 512 + (size_t)tid * 8;
  float s[8];
#pragma unroll
  for (int e = 0; e < 8; ++e) s[e] = 0.f;
  size_t base = (size_t)bh * NC * (DS * P_) + off;
  for (int c = 0; c < NC; ++c) {
    _Float16* p = Sbuf + base + (size_t)c * (DS * P_);
    f16x8 v = *(const f16x8*)p;
    f16x8 sto;
#pragma unroll
    for (int e = 0; e < 8; ++e) sto[e] = (_Float16)s[e];
    *(f16x8*)p = sto;                    // state BEFORE chunk c
    const float d = dec[c];
#pragma unroll
    for (int e = 0; e < 8; ++e) s[e] = s[e] * d + (float)v[e];
  }
}

// ---------------- inter-chunk correction + D*x (ytot fp16 RMW); local cumsum ----------------
__global__ __launch_bounds__(256)
void k_inter(const _Float16* __restrict__ xs, const _Float16* __restrict__ Cm,
             const float* __restrict__ dtv, const float* __restrict__ A_log,
             const _Float16* __restrict__ Sbuf, const float* __restrict__ Dp,
             _Float16* __restrict__ ytot)
{
  const int c = blockIdx.x, h = blockIdx.y, bz = blockIdx.z;
  const int gidx = (bz * H_ + h) * NC + c;
  __shared__ float sS[DS][SP];
  __shared__ float sC[Q_][SP];
  __shared__ float escum[Q_];
  const int tid = threadIdx.x;
  const int jr = tid >> 2, blk = (tid & 3) * 16;
  const int rowbase = bz * L_ + c * Q_;
  {
    if (tid < Q_) {
      float v = dtv[(size_t)(rowbase + tid) * H_ + h] * (-expf(A_log[h]));
#pragma unroll
      for (int off = 1; off < 64; off <<= 1) {
        float n = __shfl_up(v, off, 64);
        if (tid >= off) v += n;
      }
      escum[tid] = expf(v);
    }
    const _Float16* ssrc = Sbuf + (size_t)gidx * (DS * P_) + jr * P_ + blk;
    f16x8 sv0 = *(const f16x8*)ssrc;
    f16x8 sv1 = *(const f16x8*)(ssrc + 8);
    const _Float16* csrc = Cm + (size_t)(rowbase + jr) * DS + blk;
    f16x8 cv0 = *(const f16x8*)csrc;
    f16x8 cv1 = *(const f16x8*)(csrc + 8);
#pragma unroll
    for (int o = 0; o < 8; ++o) {
      sS[jr][blk + o]     = (float)sv0[o];
      sS[jr][blk + 8 + o] = (float)sv1[o];
      sC[jr][blk + o]     = (float)cv0[o];
      sC[jr][blk + 8 + o] = (float)cv1[o];
    }
  }
  __syncthreads();
  const int i = jr;
  f32x4 acc[4];
#pragma unroll
  for (int q = 0; q < 4; ++q) acc[q] = (f32x4){0.f, 0.f, 0.f, 0.f};
  for (int n = 0; n < DS; ++n) {
    float cv = sC[i][n];
#pragma unroll
    for (int q = 0; q < 4; ++q) acc[q] += cv * *(const f32x4*)&sS[n][blk + q * 4];
  }
  const float e = escum[i];
  const float Dh = Dp[h];
  _Float16* yt = ytot + (size_t)(rowbase + i) * DI + h * P_ + blk;
  const _Float16* xsr = xs + (size_t)(rowbase + i) * DI + h * P_ + blk;
  f16x8 xa = *(const f16x8*)xsr;
  f16x8 xb2 = *(const f16x8*)(xsr + 8);
  f16x8 y0 = *(const f16x8*)yt;
  f16x8 y1 = *(const f16x8*)(yt + 8);
#pragma unroll
  for (int o = 0; o < 16; ++o) {
    float cur = (float)((o < 8) ? y0[o] : y1[o - 8]);
    float xf  = (float)((o < 8) ? xa[o] : xb2[o - 8]);
    cur += e * acc[o >> 2][o & 3] + Dh * xf;
    if (o < 8) y0[o] = (_Float16)cur; else y1[o - 8] = (_Float16)cur;
  }
  *(f16x8*)yt = y0;
  *(f16x8*)(yt + 8) = y1;
}

// ---------------- gate (silu(z)) + RMSNorm + cast bf16 ----------------
__global__ __launch_bounds__(192)
void k_rms(const unsigned short* __restrict__ zx, const _Float16* __restrict__ ytot,
           const float* __restrict__ norm_w, unsigned short* __restrict__ ynorm)
{
  const int row = blockIdx.x, tid = threadIdx.x;
  const int e0 = tid * 8;
  us8 zv = *(const us8*)(zx + (size_t)row * N1 + e0);
  f16x8 yv = *(const f16x8*)(ytot + (size_t)row * DI + e0);
  float g[8];
  float ss = 0.f;
#pragma unroll
  for (int q = 0; q < 8; ++q) {
    g[q] = (float)yv[q] * siluf(bf2f(zv[q]));
    ss += g[q] * g[q];
  }
#pragma unroll
  for (int off = 32; off > 0; off >>= 1) ss += __shfl_down(ss, off);
  __shared__ float wsum[3];
  __shared__ float sscale;
  if ((tid & 63) == 0) wsum[tid >> 6] = ss;
  __syncthreads();
  if (tid == 0) sscale = rsqrtf((wsum[0] + wsum[1] + wsum[2]) * (1.f / DI) + 1e-5f);
  __syncthreads();
  const float sc = sscale;
  us8 o;
#pragma unroll
  for (int q = 0; q < 8; ++q) o[q] = f2bf(g[q] * sc * norm_w[e0 + q]);
  *(us8*)(ynorm + (size_t)row * DI + e0) = o;
}

extern "C" void kernel_launch(void* const* d_in, const int* in_sizes, int n_in,
                              void* d_out, int out_size, void* d_ws, size_t ws_size,
                              hipStream_t stream)
{
  (void)in_sizes; (void)n_in; (void)out_size;
  const float* x       = (const float*)d_in[0];
  const float* W_in    = (const float*)d_in[1];
  const float* conv_w  = (const float*)d_in[2];
  const float* conv_b  = (const float*)d_in[3];
  const float* dt_bias = (const float*)d_in[4];
  const float* A_log   = (const float*)d_in[5];
  const float* Dp      = (const float*)d_in[6];
  const float* norm_w  = (const float*)d_in[7];
  const float* W_out   = (const float*)d_in[8];
  float* out = (float*)d_out;

  // ---- batches per pass: footprint(nb) = nb*L_*15968 + ~14.7 MB fixed ----
  const int nb = ((size_t)2 * L_ * 15968 + 14737408 <= ws_size) ? 2 : 1;
  const int rows = nb * L_;

  // ---- workspace layout ----
  char* ws = (char*)d_ws;
  unsigned short* zx = (unsigned short*)ws;  ws += (size_t)rows * N1 * 2;   // bf16 z|xBC
  _Float16* xs   = (_Float16*)ws;  ws += (size_t)rows * DI * 2;             // fp16 conv-x
  _Float16* ytot = (_Float16*)ws;  ws += (size_t)rows * DI * 2;             // fp16 y
  _Float16* Bm   = (_Float16*)ws;  ws += (size_t)rows * DS * 2;
  _Float16* Cm   = (_Float16*)ws;  ws += (size_t)rows * DS * 2;
  float* dtv  = (float*)ws;  ws += (size_t)rows * H_ * 4;
  _Float16* Sbuf = (_Float16*)ws;  ws += (size_t)rows * 3072;  // nb*H_*NC*DS*P_*2
  unsigned short* WinT  = (unsigned short*)ws; ws += (size_t)NPJ * DM * 2;
  unsigned short* WoutT = (unsigned short*)ws; ws += (size_t)DM * DI * 2;
  float* WdtT = (float*)ws;  ws += (size_t)H_ * DM * 4;
  float* decb = (float*)ws;  ws += (size_t)nb * H_ * NC * 4;
  unsigned short* xb    = (unsigned short*)Sbuf;     // overlay: Sbuf dead until k_intra
  unsigned short* ynorm = (unsigned short*)xs;       // overlay: xs dead after k_inter

  k_transpose_cast<<<dim3(24, (NPJ + 31) / 32), 256, 0, stream>>>(W_in, WinT, DM, NPJ);
  k_transpose_cast<<<dim3(48, 24), 256, 0, stream>>>(W_out, WoutT, DI, DM);
  k_wdtT<<<(H_ * DM + 255) / 256, 256, 0, stream>>>(W_in, WdtT);

  for (int b0 = 0; b0 < B_; b0 += nb) {
    const float* xp = x + (size_t)b0 * L_ * DM;

    k_dt2<<<rows / 8, 192, 0, stream>>>(xp, WdtT, dt_bias, dtv, xb);
    k_gemm_t<256, 128, 128, 64, 64, true><<<dim3(rows / 256, N1 / 128), 256, 0, stream>>>(
        xb, WinT, zx, N1, DM);
    k_conv2<<<dim3(7, rows / CROWS), 256, 0, stream>>>(zx, conv_w, conv_b, xs, Bm, Cm);
    k_intra<<<dim3(NC, H_, nb), 256, 0, stream>>>(xs, Bm, Cm, dtv, A_log, ytot, Sbuf, decb);
    k_chunkscan<<<dim3(8, H_, nb), 64, 0, stream>>>(Sbuf, decb);
    k_inter<<<dim3(NC, H_, nb), 256, 0, stream>>>(xs, Cm, dtv, A_log, Sbuf, Dp, ytot);
    k_rms<<<rows, 192, 0, stream>>>(zx, ytot, norm_w, ynorm);
    k_gemm_t<128, 64, 64, 32, 128, false><<<dim3(rows / 128, DM / 64), 256, 0, stream>>>(
        ynorm, WoutT, out + (size_t)b0 * L_ * DM, DM, DI);
  }
}